// Round 10
// baseline (221.702 us; speedup 1.0000x reference)
//
#include <hip/hip_runtime.h>

#define B_  256
#define T_  256
#define S_  20
#define U1  32
#define G1  128   // 4*U1
#define U2  24
#define G2  96    // 4*U2

typedef __attribute__((ext_vector_type(8))) short short8;   // 8 bf16 = 4 VGPRs
typedef __attribute__((ext_vector_type(4))) float f32x4;    // MFMA acc
typedef _Float16 half2_t __attribute__((ext_vector_type(2)));

// Raw-HW activations (v_exp_f32 = 2^x, pre-scaled by log2e).
__device__ __forceinline__ float sigmoidf_(float x) {
    return __builtin_amdgcn_rcpf(1.0f + __builtin_amdgcn_exp2f(x * -1.44269504f));
}
__device__ __forceinline__ float tanhf_fast(float x) {   // 1 - 2/(1+e^{2x})
    return 1.0f - 2.0f * __builtin_amdgcn_rcpf(1.0f + __builtin_amdgcn_exp2f(x * 2.88539008f));
}

__device__ __forceinline__ unsigned short f2bf(float a) {
    unsigned int u = __float_as_uint(a);
    u += 0x7FFFu + ((u >> 16) & 1u);
    return (unsigned short)(u >> 16);
}
__device__ __forceinline__ unsigned int pack2bf(float a, float b) {
    unsigned int ua = __float_as_uint(a); ua += 0x7FFFu + ((ua >> 16) & 1u);
    unsigned int ub = __float_as_uint(b); ub += 0x7FFFu + ((ub >> 16) & 1u);
    return (ua >> 16) | (ub & 0xFFFF0000u);
}
union frag_u { short8 v; unsigned int u[4]; };
union h2u { unsigned int u32; half2_t h2; unsigned short s[2]; };

// Parallel prep: UiF (2048 u32, bf16 MFMA frags), WoF (1536), UoH (1536 u32,
// f16 pairs for the outer dot2 matvec). R9 accounting: the old 1-wave prep
// was ~15-25us of serialized scattered loads -> now 5120 threads, 1 elem each.
__global__ void prep_all(const float* __restrict__ Ui, const float* __restrict__ Wo,
                         const float* __restrict__ Uo,
                         unsigned int* __restrict__ UiF, unsigned int* __restrict__ WoF,
                         unsigned int* __restrict__ UoH) {
    const int tid = blockIdx.x * 256 + threadIdx.x;
    if (tid < 2048) {                       // UiF[(tt*64+lane)*4 + k2]
        const int k2 = tid & 3, lane = (tid >> 2) & 63, tt = tid >> 8;
        const int q = lane >> 4, n = lane & 15;
        const float e0 = Ui[(8 * q + 2 * k2) * G1 + 16 * tt + n];
        const float e1 = Ui[(8 * q + 2 * k2 + 1) * G1 + 16 * tt + n];
        UiF[tid] = pack2bf(e0, e1);
    } else if (tid < 3584) {                // WoF
        const int t2 = tid - 2048;
        const int k2 = t2 & 3, lane = (t2 >> 2) & 63, tt = t2 >> 8;
        const int q = lane >> 4, n = lane & 15;
        const float e0 = Wo[(8 * q + 2 * k2) * G2 + 16 * tt + n];
        const float e1 = Wo[(8 * q + 2 * k2 + 1) * G2 + 16 * tt + n];
        WoF[t2] = pack2bf(e0, e1);
    } else if (tid < 5120) {                // UoH[(g*12+j)*32 + u] = f16(Uo[2j][g*24+u], Uo[2j+1][..])
        const int t3 = tid - 3584;
        const int u = t3 & 31, j = (t3 >> 5) % 12, g = t3 / (32 * 12);
        h2u pk; pk.u32 = 0;
        if (u < U2) {
            pk.h2[0] = (_Float16)Uo[(2 * j) * G2 + g * U2 + u];
            pk.h2[1] = (_Float16)Uo[(2 * j + 1) * G2 + g * U2 + u];
        }
        UoH[t3] = pk.u32;
    }
}

// Inner LSTM via MFMA (bf16 in, fp32 acc) -- UNCHANGED from R9 (isolate
// measurements; with outer dropping below it, its counters surface next).
template <bool WRITE_P>
__global__ __attribute__((amdgpu_flat_work_group_size(256, 256)))
__attribute__((amdgpu_waves_per_eu(2, 2)))
void inner_kernel(
    const float* __restrict__ x, const int* __restrict__ lengths,
    const float* __restrict__ Wi, const float* __restrict__ bi,
    const uint4* __restrict__ UiF, const uint4* __restrict__ WoF,
    const float* __restrict__ bo, float* __restrict__ outbuf)
{
    __shared__ float xs[4][320];
    __shared__ unsigned short hbb[4][16][40];
    const int lane = threadIdx.x & 63;
    const int w = __builtin_amdgcn_readfirstlane((int)(threadIdx.x >> 6));
    const int q = lane >> 4;
    const int n = lane & 15;
    const int tile = blockIdx.x & 3;
    const int b = blockIdx.x >> 2;
    const int len = lengths[b];
    const int wt0 = tile * 64 + w * 16;
    if (wt0 >= len) return;                     // wave-uniform exit, no barriers

    const float* xg = x + (size_t)(b * T_ + wt0) * S_;
#pragma unroll
    for (int i = 0; i < 5; ++i) xs[w][64 * i + lane] = xg[64 * i + lane];

    frag_u Bui[8];
#pragma unroll
    for (int tt = 0; tt < 8; ++tt) {
        uint4 v = UiF[tt * 64 + lane];
        Bui[tt].u[0] = v.x; Bui[tt].u[1] = v.y; Bui[tt].u[2] = v.z; Bui[tt].u[3] = v.w;
    }
    float bi_l[8], Wi_l[8];
#pragma unroll
    for (int tt = 0; tt < 8; ++tt) { bi_l[tt] = bi[16 * tt + n]; Wi_l[tt] = Wi[16 * tt + n]; }

    float c[2][4];
#pragma unroll
    for (int uh = 0; uh < 2; ++uh)
#pragma unroll
        for (int r = 0; r < 4; ++r) c[uh][r] = 0.0f;

    // peeled s = 0 (h == 0: no MFMA)
    {
        float x0[4];
#pragma unroll
        for (int r = 0; r < 4; ++r) x0[r] = xs[w][(4 * q + r) * S_];
        f32x4 acc[8];
#pragma unroll
        for (int tt = 0; tt < 8; ++tt)
#pragma unroll
            for (int r = 0; r < 4; ++r)
                acc[tt][r] = bi_l[tt] + x0[r] * Wi_l[tt];
#pragma unroll
        for (int uh = 0; uh < 2; ++uh)
#pragma unroll
            for (int r = 0; r < 4; ++r) {
                const float iv = sigmoidf_(acc[0 + uh][r]);
                const float fv = sigmoidf_(acc[2 + uh][r]);
                const float gv = tanhf_fast(acc[4 + uh][r]);
                const float ov = sigmoidf_(acc[6 + uh][r]);
                c[uh][r] = fv * c[uh][r] + iv * gv;
                hbb[w][4 * q + r][n + 16 * uh] = f2bf(ov * tanhf_fast(c[uh][r]));
            }
    }

    float xc[4];
#pragma unroll
    for (int r = 0; r < 4; ++r) xc[r] = xs[w][(4 * q + r) * S_ + 1];

#pragma unroll 1
    for (int s = 1; s < S_; ++s) {
        const int sn = (s + 1 < S_) ? s + 1 : S_ - 1;
        float xnx[4];
#pragma unroll
        for (int r = 0; r < 4; ++r) xnx[r] = xs[w][(4 * q + r) * S_ + sn];

        f32x4 acc[8];
#pragma unroll
        for (int tt = 0; tt < 8; ++tt)
#pragma unroll
            for (int r = 0; r < 4; ++r)
                acc[tt][r] = bi_l[tt] + xc[r] * Wi_l[tt];

        const short8 A = *(const short8*)&hbb[w][n][8 * q];  // ds_read_b128
#pragma unroll
        for (int tt = 0; tt < 8; ++tt)
            acc[tt] = __builtin_amdgcn_mfma_f32_16x16x32_bf16(A, Bui[tt].v, acc[tt], 0, 0, 0);

#pragma unroll
        for (int uh = 0; uh < 2; ++uh)
#pragma unroll
            for (int r = 0; r < 4; ++r) {
                const float iv = sigmoidf_(acc[0 + uh][r]);
                const float fv = sigmoidf_(acc[2 + uh][r]);
                const float gv = tanhf_fast(acc[4 + uh][r]);
                const float ov = sigmoidf_(acc[6 + uh][r]);
                c[uh][r] = fv * c[uh][r] + iv * gv;
                hbb[w][4 * q + r][n + 16 * uh] = f2bf(ov * tanhf_fast(c[uh][r]));
            }
#pragma unroll
        for (int r = 0; r < 4; ++r) xc[r] = xnx[r];
    }

    if constexpr (WRITE_P) {
        frag_u Bwo[6];
#pragma unroll
        for (int tt = 0; tt < 6; ++tt) {
            uint4 v = WoF[tt * 64 + lane];
            Bwo[tt].u[0] = v.x; Bwo[tt].u[1] = v.y; Bwo[tt].u[2] = v.z; Bwo[tt].u[3] = v.w;
        }
        const short8 A = *(const short8*)&hbb[w][n][8 * q];
        f32x4 accp[6];
#pragma unroll
        for (int tt = 0; tt < 6; ++tt) {
            const float bv = bo[16 * tt + n];
#pragma unroll
            for (int r = 0; r < 4; ++r) accp[tt][r] = bv;
            accp[tt] = __builtin_amdgcn_mfma_f32_16x16x32_bf16(A, Bwo[tt].v, accp[tt], 0, 0, 0);
        }
#pragma unroll
        for (int r = 0; r < 4; ++r) {
            const int t_row = wt0 + 4 * q + r;
            if (t_row < len) {
                float* Pr = outbuf + (size_t)(b * T_ + t_row) * G2 + n;
#pragma unroll
                for (int tt = 0; tt < 6; ++tt) Pr[16 * tt] = accp[tt][r];
            }
        }
    } else {
#pragma unroll
        for (int r = 0; r < 4; ++r) {
            const int t_row = wt0 + 4 * q + r;
            if (t_row < len) {
                float* Fr = outbuf + (size_t)(b * T_ + t_row) * U1;
#pragma unroll
                for (int uh = 0; uh < 2; ++uh)
                    Fr[n + 16 * uh] = __uint_as_float((unsigned)hbb[w][4 * q + r][n + 16 * uh] << 16);
            }
        }
    }
}

// Outer LSTM + head: 1 wave/seq, ALL 4 GATES per lane (lane u<24 owns unit u)
// via v_dot2_f32_f16: 48 dot2 = 96-cyc issue (same as R7's half-split's 48
// FMAs) but with NO shfl_xor -- removes ~130 cyc of LDS-pipe latency from the
// 256-step serial chain (R9 showed the chain, not weight refetch, is the
// whole 690 cyc/step). h broadcast as f16 pairs: 24 readlane + 12 SALU packs
// (SALU issues parallel to VALU). Weights: 48 half2 VGPRs, resident via
// waves_per_eu(1,1) (proven R9: VGPR 36->132).
__global__ __attribute__((amdgpu_flat_work_group_size(64, 64)))
__attribute__((amdgpu_waves_per_eu(1, 1)))
void outer_kernel_p(
    const float* __restrict__ P,        // [B*T*G2]
    const int*   __restrict__ lengths,  // [B]
    const unsigned int* __restrict__ UoH, // [4*12*32] f16 pairs
    const float* __restrict__ Wd,       // [U2]
    const float* __restrict__ bd,       // [1]
    float* __restrict__ out)            // [B]
{
    const int b = blockIdx.x;
    const int lane = threadIdx.x;
    const int u = (lane < U2) ? lane : U2 - 1;

    // w2[g][j] = (Uo[2j][g*24+u], Uo[2j+1][g*24+u]) as half2; 48 VGPRs
    h2u w2[4][12];
#pragma unroll
    for (int g = 0; g < 4; ++g)
#pragma unroll
        for (int j = 0; j < 12; ++j)
            w2[g][j].u32 = UoH[(g * 12 + j) * 32 + u];

    const int len = lengths[b];              // >= 1
    const float* Pb = P + (size_t)b * T_ * G2;

    float cu, hu;
    float p0[4], p1[4], p2[4];
#pragma unroll
    for (int g = 0; g < 4; ++g) {
        const int t1 = (1 < len) ? 1 : len - 1;
        const int t2 = (2 < len) ? 2 : len - 1;
        p0[g] = Pb[g * U2 + u];
        p1[g] = Pb[(size_t)t1 * G2 + g * U2 + u];
        p2[g] = Pb[(size_t)t2 * G2 + g * U2 + u];
    }

    // ---- peeled t = 0 (h == 0, c == 0): z = P row only ----
    {
        const float ig = sigmoidf_(p0[0]);
        const float gg = tanhf_fast(p0[2]);
        const float og = sigmoidf_(p0[3]);
        cu = ig * gg;
        hu = og * tanhf_fast(cu);
#pragma unroll
        for (int g = 0; g < 4; ++g) { p0[g] = p1[g]; p1[g] = p2[g]; }
        const int tn = (3 < len) ? 3 : len - 1;
#pragma unroll
        for (int g = 0; g < 4; ++g) p2[g] = Pb[(size_t)tn * G2 + g * U2 + u];
    }

    // ---- steady state ----
#pragma unroll 1
    for (int t = 1; t < len; ++t) {
        const int tn = (t + 3 < len) ? (t + 3) : (len - 1);
        float pn[4];
#pragma unroll
        for (int g = 0; g < 4; ++g) pn[g] = Pb[(size_t)tn * G2 + g * U2 + u];

        // f16 image of hu for the packed broadcast (RTN cast)
        const _Float16 hf = (_Float16)hu;
        const unsigned int h16 = (unsigned int)*(const unsigned short*)&hf;

        float z[4];
#pragma unroll
        for (int g = 0; g < 4; ++g) z[g] = p0[g];

#pragma unroll
        for (int j = 0; j < 12; ++j) {
            const unsigned int lo = (unsigned int)__builtin_amdgcn_readlane((int)h16, 2 * j);
            const unsigned int hi = (unsigned int)__builtin_amdgcn_readlane((int)h16, 2 * j + 1);
            h2u hp; hp.u32 = lo | (hi << 16);   // SALU pack, uniform
#if __has_builtin(__builtin_amdgcn_fdot2)
#pragma unroll
            for (int g = 0; g < 4; ++g)
                z[g] = __builtin_amdgcn_fdot2(hp.h2, w2[g][j].h2, z[g], false);
#else
#pragma unroll
            for (int g = 0; g < 4; ++g)
                z[g] += (float)hp.h2[0] * (float)w2[g][j].h2[0]
                      + (float)hp.h2[1] * (float)w2[g][j].h2[1];
#endif
        }

        const float ig = sigmoidf_(z[0]);
        const float fg = sigmoidf_(z[1]);
        const float gg = tanhf_fast(z[2]);
        const float og = sigmoidf_(z[3]);
        cu = fg * cu + ig * gg;
        hu = og * tanhf_fast(cu);

#pragma unroll
        for (int g = 0; g < 4; ++g) { p0[g] = p1[g]; p1[g] = p2[g]; p2[g] = pn[g]; }
    }

    float acc = bd[0];
#pragma unroll
    for (int k = 0; k < U2; ++k)
        acc += __int_as_float(__builtin_amdgcn_readlane(__float_as_int(hu), k)) * Wd[k];
    if (lane == 0) out[b] = sigmoidf_(acc);
}

// Fallback outer (feats path), unchanged.
__global__ __attribute__((amdgpu_flat_work_group_size(64, 64)))
__attribute__((amdgpu_waves_per_eu(1, 1)))
void outer_kernel_f(
    const float* __restrict__ feats, const int* __restrict__ lengths,
    const float* __restrict__ Wo, const float* __restrict__ Uo,
    const float* __restrict__ bo, const float* __restrict__ Wd,
    const float* __restrict__ bd, float* __restrict__ out)
{
    const int b = blockIdx.x;
    const int lane = threadIdx.x;
    const int u = (lane < U2) ? lane : U2 - 1;

    float wu[4][U2], wx[4][U1], bz[4];
#pragma unroll
    for (int g = 0; g < 4; ++g) {
        bz[g] = bo[g * U2 + u];
#pragma unroll
        for (int k = 0; k < U2; ++k) wu[g][k] = Uo[k * G2 + g * U2 + u];
#pragma unroll
        for (int k = 0; k < U1; ++k) wx[g][k] = Wo[k * G2 + g * U2 + u];
    }

    const int len = lengths[b];
    const float* Fb = feats + (size_t)b * T_ * U1;
    float cu, hu;

    {   // t = 0 peeled
        float z[4];
#pragma unroll
        for (int g = 0; g < 4; ++g) z[g] = bz[g];
#pragma unroll
        for (int k = 0; k < U1; ++k) {
            const float fk = Fb[k];
#pragma unroll
            for (int g = 0; g < 4; ++g) z[g] += fk * wx[g][k];
        }
        const float ig = sigmoidf_(z[0]);
        const float gg = tanhf_fast(z[2]);
        const float og = sigmoidf_(z[3]);
        cu = ig * gg;
        hu = og * tanhf_fast(cu);
    }

#pragma unroll 1
    for (int t = 1; t < len; ++t) {
        float z[4];
#pragma unroll
        for (int g = 0; g < 4; ++g) z[g] = bz[g];
        const float* Ft = Fb + (size_t)t * U1;
#pragma unroll
        for (int k = 0; k < U1; ++k) {
            const float fk = Ft[k];
#pragma unroll
            for (int g = 0; g < 4; ++g) z[g] += fk * wx[g][k];
        }
#pragma unroll
        for (int k = 0; k < U2; ++k) {
            const float hk = __int_as_float(__builtin_amdgcn_readlane(__float_as_int(hu), k));
#pragma unroll
            for (int g = 0; g < 4; ++g) z[g] += hk * wu[g][k];
        }
        const float ig = sigmoidf_(z[0]);
        const float fg = sigmoidf_(z[1]);
        const float gg = tanhf_fast(z[2]);
        const float og = sigmoidf_(z[3]);
        cu = fg * cu + ig * gg;
        hu = og * tanhf_fast(cu);
    }

    float acc = bd[0];
#pragma unroll
    for (int k = 0; k < U2; ++k)
        acc += __int_as_float(__builtin_amdgcn_readlane(__float_as_int(hu), k)) * Wd[k];
    if (lane == 0) out[b] = sigmoidf_(acc);
}

extern "C" void kernel_launch(void* const* d_in, const int* in_sizes, int n_in,
                              void* d_out, int out_size, void* d_ws, size_t ws_size,
                              hipStream_t stream) {
    const float* x       = (const float*)d_in[0];
    const int*   lengths = (const int*)  d_in[1];
    const float* Wi      = (const float*)d_in[2];
    const float* Ui      = (const float*)d_in[3];
    const float* bi      = (const float*)d_in[4];
    const float* Wo      = (const float*)d_in[5];
    const float* Uo      = (const float*)d_in[6];
    const float* bo      = (const float*)d_in[7];
    const float* Wd      = (const float*)d_in[8];
    const float* bd      = (const float*)d_in[9];
    float* out = (float*)d_out;

    // ws: [UiF 8KB @0][WoF 6KB @8192][UoH 6KB @14336][pad to 24576][P/feats]
    unsigned int* UiF = (unsigned int*)d_ws;
    unsigned int* WoF = UiF + 2048;
    unsigned int* UoH = UiF + 3584;
    float* data = (float*)((char*)d_ws + 24576);
    const size_t P_BYTES = (size_t)B_ * T_ * G2 * sizeof(float);   // 25.2 MB

    prep_all<<<dim3(20), dim3(256), 0, stream>>>(Ui, Wo, Uo, UiF, WoF, UoH);

    if (ws_size >= 24576 + P_BYTES) {
        inner_kernel<true><<<dim3(B_ * T_ / 64), dim3(256), 0, stream>>>(
            x, lengths, Wi, bi, (const uint4*)UiF, (const uint4*)WoF, bo, data);
        outer_kernel_p<<<dim3(B_), dim3(64), 0, stream>>>(
            data, lengths, UoH, Wd, bd, out);
    } else {
        inner_kernel<false><<<dim3(B_ * T_ / 64), dim3(256), 0, stream>>>(
            x, lengths, Wi, bi, (const uint4*)UiF, (const uint4*)WoF, bo, data);
        outer_kernel_f<<<dim3(B_), dim3(64), 0, stream>>>(
            data, lengths, Wo, Uo, bo, Wd, bd, out);
    }
}

// Round 11
// 182.300 us; speedup vs baseline: 1.2161x; 1.2161x over previous
//
#include <hip/hip_runtime.h>

#define B_  256
#define T_  256
#define S_  20
#define U1  32
#define G1  128   // 4*U1
#define U2  24
#define G2  96    // 4*U2

typedef __attribute__((ext_vector_type(8))) short short8;   // 8 bf16 = 4 VGPRs
typedef __attribute__((ext_vector_type(4))) float f32x4;    // MFMA acc

// Raw-HW activations (v_exp_f32 = 2^x, pre-scaled by log2e). R7: 134->74us.
__device__ __forceinline__ float sigmoidf_(float x) {
    return __builtin_amdgcn_rcpf(1.0f + __builtin_amdgcn_exp2f(x * -1.44269504f));
}
__device__ __forceinline__ float tanhf_fast(float x) {   // 1 - 2/(1+e^{2x})
    return 1.0f - 2.0f * __builtin_amdgcn_rcpf(1.0f + __builtin_amdgcn_exp2f(x * 2.88539008f));
}

__device__ __forceinline__ unsigned short f2bf(float a) {
    unsigned int u = __float_as_uint(a);
    u += 0x7FFFu + ((u >> 16) & 1u);
    return (unsigned short)(u >> 16);
}
__device__ __forceinline__ unsigned int pack2bf(float a, float b) {
    unsigned int ua = __float_as_uint(a); ua += 0x7FFFu + ((ua >> 16) & 1u);
    unsigned int ub = __float_as_uint(b); ub += 0x7FFFu + ((ub >> 16) & 1u);
    return (ua >> 16) | (ub & 0xFFFF0000u);
}
union frag_u { short8 v; unsigned int u[4]; };

// FUSED kernel: one block per sequence b, 512 threads (8 waves), 1 block/CU.
// Phase 1 (inner LSTM, MFMA): 8 waves x 2 rounds cover 16 t-tiles of 16 rows;
//   each wave runs the R9 MFMA inner (bf16 h via per-wave LDS, Ui fragments
//   resident in VGPRs) and writes its P tile (bo + h@Wo) into LDS as f16.
// __syncthreads (the ONLY barrier).
// Phase 2 (outer LSTM + head): wave 0 runs the proven R8 74us recurrence
//   (half-split gates, fp32 FMA, readlane h-broadcast, 2 shfl_xor) reading
//   P from LDS; waves 1-7 retire.
// Wins vs the 3-kernel pipeline: 2 launch/drain boundaries gone, 25 MB P
// HBM round-trip gone, prep kernel gone (fragments packed in-kernel, once).
__global__ __attribute__((amdgpu_flat_work_group_size(512, 512)))
__attribute__((amdgpu_waves_per_eu(2, 2)))
void fused_kernel(
    const float* __restrict__ x,        // [B*T*S]
    const int*   __restrict__ lengths,  // [B]
    const float* __restrict__ Wi,       // [G1]
    const float* __restrict__ Ui,       // [U1*G1]
    const float* __restrict__ bi,       // [G1]
    const float* __restrict__ Wo,       // [U1*G2]
    const float* __restrict__ Uo,       // [U2*G2]
    const float* __restrict__ bo,       // [G2]
    const float* __restrict__ Wd,       // [U2]
    const float* __restrict__ bd,       // [1]
    float* __restrict__ out)            // [B]
{
    __shared__ __align__(16) _Float16      Pl[T_][G2];      // 48 KB
    __shared__ __align__(16) unsigned short hbb[8][16][40]; // 10 KB
    const int b    = blockIdx.x;
    const int len  = lengths[b];                 // >= 1
    const int tid  = threadIdx.x;
    const int w    = __builtin_amdgcn_readfirstlane(tid >> 6);   // wave 0..7
    const int lane = tid & 63;
    const int q    = lane >> 4;                  // quad
    const int n    = lane & 15;                  // col-in-tile / A-row

    // ---- one-time per-wave fragment & bias loads (scalar weight addrs) ----
    frag_u Bui[8];
#pragma unroll
    for (int tt = 0; tt < 8; ++tt)
#pragma unroll
        for (int k2 = 0; k2 < 4; ++k2)
            Bui[tt].u[k2] = pack2bf(Ui[(8 * q + 2 * k2) * G1 + 16 * tt + n],
                                    Ui[(8 * q + 2 * k2 + 1) * G1 + 16 * tt + n]);
    frag_u Bwo[6];
#pragma unroll
    for (int tt = 0; tt < 6; ++tt)
#pragma unroll
        for (int k2 = 0; k2 < 4; ++k2)
            Bwo[tt].u[k2] = pack2bf(Wo[(8 * q + 2 * k2) * G2 + 16 * tt + n],
                                    Wo[(8 * q + 2 * k2 + 1) * G2 + 16 * tt + n]);
    float bi_l[8], Wi_l[8], bo_l[6];
#pragma unroll
    for (int tt = 0; tt < 8; ++tt) { bi_l[tt] = bi[16 * tt + n]; Wi_l[tt] = Wi[16 * tt + n]; }
#pragma unroll
    for (int tt = 0; tt < 6; ++tt) bo_l[tt] = bo[16 * tt + n];

    // ================= phase 1: inner LSTM, 2 rounds of 16-row tiles =======
#pragma unroll 1
    for (int round = 0; round < 2; ++round) {
        const int wt0 = (w + 8 * round) * 16;    // tile's first t
        if (wt0 < len) {                         // wave-uniform; skip to barrier
            // per-row x pointers (lanes in a quad share the row -> broadcastable)
            const float* xr = x + (size_t)(b * T_ + wt0 + 4 * q) * S_;

            float c[2][4];
#pragma unroll
            for (int uh = 0; uh < 2; ++uh)
#pragma unroll
                for (int r = 0; r < 4; ++r) c[uh][r] = 0.0f;

            float xc[4];
#pragma unroll
            for (int r = 0; r < 4; ++r) xc[r] = xr[r * S_];

            // peeled s = 0 (h == 0: no MFMA)
            {
                f32x4 acc[8];
#pragma unroll
                for (int tt = 0; tt < 8; ++tt)
#pragma unroll
                    for (int r = 0; r < 4; ++r)
                        acc[tt][r] = bi_l[tt] + xc[r] * Wi_l[tt];
#pragma unroll
                for (int uh = 0; uh < 2; ++uh)
#pragma unroll
                    for (int r = 0; r < 4; ++r) {
                        const float iv = sigmoidf_(acc[0 + uh][r]);
                        const float fv = sigmoidf_(acc[2 + uh][r]);
                        const float gv = tanhf_fast(acc[4 + uh][r]);
                        const float ov = sigmoidf_(acc[6 + uh][r]);
                        c[uh][r] = fv * c[uh][r] + iv * gv;
                        hbb[w][4 * q + r][n + 16 * uh] = f2bf(ov * tanhf_fast(c[uh][r]));
                    }
            }
#pragma unroll
            for (int r = 0; r < 4; ++r) xc[r] = xr[r * S_ + 1];

            // steady state s = 1..19: unconditional MFMA (fragments resident)
#pragma unroll 1
            for (int s = 1; s < S_; ++s) {
                const int sn = (s + 1 < S_) ? s + 1 : S_ - 1;
                float xnx[4];
#pragma unroll
                for (int r = 0; r < 4; ++r) xnx[r] = xr[r * S_ + sn];

                f32x4 acc[8];
#pragma unroll
                for (int tt = 0; tt < 8; ++tt)
#pragma unroll
                    for (int r = 0; r < 4; ++r)
                        acc[tt][r] = bi_l[tt] + xc[r] * Wi_l[tt];

                const short8 A = *(const short8*)&hbb[w][n][8 * q];  // ds_read_b128
#pragma unroll
                for (int tt = 0; tt < 8; ++tt)
                    acc[tt] = __builtin_amdgcn_mfma_f32_16x16x32_bf16(A, Bui[tt].v, acc[tt], 0, 0, 0);

#pragma unroll
                for (int uh = 0; uh < 2; ++uh)
#pragma unroll
                    for (int r = 0; r < 4; ++r) {
                        const float iv = sigmoidf_(acc[0 + uh][r]);
                        const float fv = sigmoidf_(acc[2 + uh][r]);
                        const float gv = tanhf_fast(acc[4 + uh][r]);
                        const float ov = sigmoidf_(acc[6 + uh][r]);
                        c[uh][r] = fv * c[uh][r] + iv * gv;
                        hbb[w][4 * q + r][n + 16 * uh] = f2bf(ov * tanhf_fast(c[uh][r]));
                    }
#pragma unroll
                for (int r = 0; r < 4; ++r) xc[r] = xnx[r];
            }

            // P tile = bo + h @ Wo -> LDS f16 (rows >= len written but never read)
            {
                const short8 A = *(const short8*)&hbb[w][n][8 * q];
                f32x4 accp[6];
#pragma unroll
                for (int tt = 0; tt < 6; ++tt) {
#pragma unroll
                    for (int r = 0; r < 4; ++r) accp[tt][r] = bo_l[tt];
                    accp[tt] = __builtin_amdgcn_mfma_f32_16x16x32_bf16(A, Bwo[tt].v, accp[tt], 0, 0, 0);
                }
#pragma unroll
                for (int r = 0; r < 4; ++r) {
                    const int tr = wt0 + 4 * q + r;
#pragma unroll
                    for (int tt = 0; tt < 6; ++tt)
                        Pl[tr][16 * tt + n] = (_Float16)accp[tt][r];
                }
            }
        }
    }

    __syncthreads();                             // the only barrier
    if (tid >= 64) return;                       // waves 1-7 retire

    // ================= phase 2: outer LSTM + head (wave 0, R8 form) ========
    const int half = lane >> 5;                  // 0: gates i,f  1: gates g,o
    const int sub  = lane & 31;
    const int u    = (sub < U2) ? sub : U2 - 1;
    const int gA   = 2 * half;
    const int gB   = 2 * half + 1;

    float wA[U2], wB[U2];                        // 48 weight VGPRs
#pragma unroll
    for (int k = 0; k < U2; ++k) {
        wA[k] = Uo[k * G2 + gA * U2 + u];
        wB[k] = Uo[k * G2 + gB * U2 + u];
    }

    float cu, hu;
    float pA0 = (float)Pl[0][gA * U2 + u];
    float pB0 = (float)Pl[0][gB * U2 + u];

    // peeled t = 0 (h == 0, c == 0): z = P row only
    {
        const float zA = pA0, zB = pB0;
        const float oA = __shfl_xor(zA, 32);
        const float oB = __shfl_xor(zB, 32);
        const float z_i = half ? oA : zA;
        const float z_g = half ? zA : oA;
        const float z_o = half ? zB : oB;
        const float ig = sigmoidf_(z_i);
        const float gg = tanhf_fast(z_g);
        const float og = sigmoidf_(z_o);
        cu = ig * gg;
        hu = og * tanhf_fast(cu);
        const int t1 = (1 < len) ? 1 : 0;
        pA0 = (float)Pl[t1][gA * U2 + u];
        pB0 = (float)Pl[t1][gB * U2 + u];
    }

    // steady state t = 1..len-1 (LDS P, 1-step prefetch ring)
#pragma unroll 1
    for (int t = 1; t < len; ++t) {
        const int tn = (t + 1 < len) ? (t + 1) : (len - 1);
        const float pAn = (float)Pl[tn][gA * U2 + u];   // prefetch next row
        const float pBn = (float)Pl[tn][gB * U2 + u];

        float zA0 = pA0, zA1 = 0.0f, zB0 = pB0, zB1 = 0.0f;
#pragma unroll
        for (int k = 0; k < U2; ++k) {
            const float hk = __int_as_float(
                __builtin_amdgcn_readlane(__float_as_int(hu), k));   // uniform idx
            if (k & 1) { zA1 += hk * wA[k]; zB1 += hk * wB[k]; }
            else       { zA0 += hk * wA[k]; zB0 += hk * wB[k]; }
        }
        const float zA = zA0 + zA1;              // half0: z_i ; half1: z_g
        const float zB = zB0 + zB1;              // half0: z_f ; half1: z_o
        const float oA = __shfl_xor(zA, 32);
        const float oB = __shfl_xor(zB, 32);

        const float z_i = half ? oA : zA;
        const float z_f = half ? oB : zB;
        const float z_g = half ? zA : oA;
        const float z_o = half ? zB : oB;

        const float ig = sigmoidf_(z_i);
        const float fg = sigmoidf_(z_f);
        const float gg = tanhf_fast(z_g);
        const float og = sigmoidf_(z_o);
        cu = fg * cu + ig * gg;
        hu = og * tanhf_fast(cu);                // identical on both halves

        pA0 = pAn; pB0 = pBn;
    }

    // dense sigmoid head
    float acc = bd[0];
#pragma unroll
    for (int k = 0; k < U2; ++k)
        acc += __int_as_float(__builtin_amdgcn_readlane(__float_as_int(hu), k)) * Wd[k];
    if (lane == 0) out[b] = sigmoidf_(acc);
}

extern "C" void kernel_launch(void* const* d_in, const int* in_sizes, int n_in,
                              void* d_out, int out_size, void* d_ws, size_t ws_size,
                              hipStream_t stream) {
    const float* x       = (const float*)d_in[0];
    const int*   lengths = (const int*)  d_in[1];
    const float* Wi      = (const float*)d_in[2];
    const float* Ui      = (const float*)d_in[3];
    const float* bi      = (const float*)d_in[4];
    const float* Wo      = (const float*)d_in[5];
    const float* Uo      = (const float*)d_in[6];
    const float* bo      = (const float*)d_in[7];
    const float* Wd      = (const float*)d_in[8];
    const float* bd      = (const float*)d_in[9];
    float* out = (float*)d_out;

    fused_kernel<<<dim3(B_), dim3(512), 0, stream>>>(
        x, lengths, Wi, Ui, bi, Wo, Uo, bo, Wd, bd, out);
}

// Round 12
// 161.657 us; speedup vs baseline: 1.3714x; 1.1277x over previous
//
#include <hip/hip_runtime.h>

#define B_  256
#define T_  256
#define S_  20
#define U1  32
#define G1  128   // 4*U1
#define U2  24
#define G2  96    // 4*U2
#define NT  16    // 16-row t-tiles per sequence

typedef __attribute__((ext_vector_type(8))) short short8;   // 8 bf16 = 4 VGPRs
typedef __attribute__((ext_vector_type(4))) float f32x4;    // MFMA acc

// Raw-HW activations (v_exp_f32 = 2^x, pre-scaled by log2e). R7: 134->74us.
__device__ __forceinline__ float sigmoidf_(float x) {
    return __builtin_amdgcn_rcpf(1.0f + __builtin_amdgcn_exp2f(x * -1.44269504f));
}
__device__ __forceinline__ float tanhf_fast(float x) {   // 1 - 2/(1+e^{2x})
    return 1.0f - 2.0f * __builtin_amdgcn_rcpf(1.0f + __builtin_amdgcn_exp2f(x * 2.88539008f));
}

__device__ __forceinline__ unsigned short f2bf(float a) {
    unsigned int u = __float_as_uint(a);
    u += 0x7FFFu + ((u >> 16) & 1u);
    return (unsigned short)(u >> 16);
}
__device__ __forceinline__ unsigned int pack2bf(float a, float b) {
    unsigned int ua = __float_as_uint(a); ua += 0x7FFFu + ((ua >> 16) & 1u);
    unsigned int ub = __float_as_uint(b); ub += 0x7FFFu + ((ub >> 16) & 1u);
    return (ua >> 16) | (ub & 0xFFFF0000u);
}
union frag_u { short8 v; unsigned int u[4]; };
union h2x  { unsigned int u32; _Float16 h[2]; };

// FUSED producer-consumer kernel: 1 block/sequence, 512 threads (8 waves).
// Producers (all waves): MFMA inner LSTM per 16-row tile; P tile -> LDS f16
//   in UNIT-MAJOR pair layout [t][u][4 gates]; per-tile flag released after.
// Consumer (wave 0, after producing tile 0 only): outer recurrence reading
//   P from LDS (one ds_read_b64/step, converted off-chain), spin-waits on a
//   tile's flag only when the prefetch crosses a tile boundary.
// vs R11: the monolithic __syncthreads made phase1 (~44us) strictly serial
// with phase2 (~74us); pipelining hides phase1 under phase2.
__global__ __attribute__((amdgpu_flat_work_group_size(512, 512)))
__attribute__((amdgpu_waves_per_eu(2, 2)))
void fused_kernel(
    const float* __restrict__ x,        // [B*T*S]
    const int*   __restrict__ lengths,  // [B]
    const float* __restrict__ Wi,       // [G1]
    const float* __restrict__ Ui,       // [U1*G1]
    const float* __restrict__ bi,       // [G1]
    const float* __restrict__ Wo,       // [U1*G2]
    const float* __restrict__ Uo,       // [U2*G2]
    const float* __restrict__ bo,       // [G2]
    const float* __restrict__ Wd,       // [U2]
    const float* __restrict__ bd,       // [1]
    float* __restrict__ out)            // [B]
{
    __shared__ __align__(16) _Float16      Pl[T_][G2];      // [t][u*4+g], 48 KB
    __shared__ __align__(16) unsigned short hbb[8][16][40]; // per-wave h tiles
    __shared__ unsigned int flags[NT];
    const int b    = blockIdx.x;
    const int len  = lengths[b];                 // >= 1
    const int tid  = threadIdx.x;
    const int w    = __builtin_amdgcn_readfirstlane(tid >> 6);   // wave 0..7
    const int lane = tid & 63;
    const int q    = lane >> 4;
    const int n    = lane & 15;

    if (tid < NT) flags[tid] = 0;
    __syncthreads();                             // only barrier: flag init

    // ---- one-time fragment/bias loads (all waves produce) ----
    frag_u Bui[8];
#pragma unroll
    for (int tt = 0; tt < 8; ++tt)
#pragma unroll
        for (int k2 = 0; k2 < 4; ++k2)
            Bui[tt].u[k2] = pack2bf(Ui[(8 * q + 2 * k2) * G1 + 16 * tt + n],
                                    Ui[(8 * q + 2 * k2 + 1) * G1 + 16 * tt + n]);
    frag_u Bwo[6];
#pragma unroll
    for (int tt = 0; tt < 6; ++tt)
#pragma unroll
        for (int k2 = 0; k2 < 4; ++k2)
            Bwo[tt].u[k2] = pack2bf(Wo[(8 * q + 2 * k2) * G2 + 16 * tt + n],
                                    Wo[(8 * q + 2 * k2 + 1) * G2 + 16 * tt + n]);
    float bi_l[8], Wi_l[8], bo_l[6];
#pragma unroll
    for (int tt = 0; tt < 8; ++tt) { bi_l[tt] = bi[16 * tt + n]; Wi_l[tt] = Wi[16 * tt + n]; }
#pragma unroll
    for (int tt = 0; tt < 6; ++tt) bo_l[tt] = bo[16 * tt + n];
    // P-store targets: col=16tt+n -> (g=col/24, u=col%24) -> offset u*4+g
    int pcol[6];
#pragma unroll
    for (int tt = 0; tt < 6; ++tt) {
        const int col = 16 * tt + n;
        const int g = col / 24;
        pcol[tt] = (col - 24 * g) * 4 + g;
    }

    // ---- tile worklist: wave0 gets only tile 0 (starts consuming ASAP);
    //      wave1 gets {1,8,9} so early tiles land first; others {w, w+8}.
    int tl[3]; int ntl;
    if (w == 0)      { tl[0] = 0; tl[1] = 0; tl[2] = 0; ntl = 1; }
    else if (w == 1) { tl[0] = 1; tl[1] = 8; tl[2] = 9; ntl = 3; }
    else             { tl[0] = w; tl[1] = w + 8; tl[2] = 0; ntl = 2; }

#pragma unroll 1
    for (int i = 0; i < ntl; ++i) {
        const int tile = tl[i];
        const int wt0  = tile * 16;
        if (wt0 >= len) break;                   // lists increasing: later also masked

        const float* xr = x + (size_t)(b * T_ + wt0 + 4 * q) * S_;
        float c[2][4];
#pragma unroll
        for (int uh = 0; uh < 2; ++uh)
#pragma unroll
            for (int r = 0; r < 4; ++r) c[uh][r] = 0.0f;

        float xc[4];
#pragma unroll
        for (int r = 0; r < 4; ++r) xc[r] = xr[r * S_];

        // peeled s = 0 (h == 0: no MFMA)
        {
            f32x4 acc[8];
#pragma unroll
            for (int tt = 0; tt < 8; ++tt)
#pragma unroll
                for (int r = 0; r < 4; ++r)
                    acc[tt][r] = bi_l[tt] + xc[r] * Wi_l[tt];
#pragma unroll
            for (int uh = 0; uh < 2; ++uh)
#pragma unroll
                for (int r = 0; r < 4; ++r) {
                    const float iv = sigmoidf_(acc[0 + uh][r]);
                    const float fv = sigmoidf_(acc[2 + uh][r]);
                    const float gv = tanhf_fast(acc[4 + uh][r]);
                    const float ov = sigmoidf_(acc[6 + uh][r]);
                    c[uh][r] = fv * c[uh][r] + iv * gv;
                    hbb[w][4 * q + r][n + 16 * uh] = f2bf(ov * tanhf_fast(c[uh][r]));
                }
        }
#pragma unroll
        for (int r = 0; r < 4; ++r) xc[r] = xr[r * S_ + 1];

        // steady state s = 1..19
#pragma unroll 1
        for (int s = 1; s < S_; ++s) {
            const int sn = (s + 1 < S_) ? s + 1 : S_ - 1;
            float xnx[4];
#pragma unroll
            for (int r = 0; r < 4; ++r) xnx[r] = xr[r * S_ + sn];

            f32x4 acc[8];
#pragma unroll
            for (int tt = 0; tt < 8; ++tt)
#pragma unroll
                for (int r = 0; r < 4; ++r)
                    acc[tt][r] = bi_l[tt] + xc[r] * Wi_l[tt];

            const short8 A = *(const short8*)&hbb[w][n][8 * q];
#pragma unroll
            for (int tt = 0; tt < 8; ++tt)
                acc[tt] = __builtin_amdgcn_mfma_f32_16x16x32_bf16(A, Bui[tt].v, acc[tt], 0, 0, 0);

#pragma unroll
            for (int uh = 0; uh < 2; ++uh)
#pragma unroll
                for (int r = 0; r < 4; ++r) {
                    const float iv = sigmoidf_(acc[0 + uh][r]);
                    const float fv = sigmoidf_(acc[2 + uh][r]);
                    const float gv = tanhf_fast(acc[4 + uh][r]);
                    const float ov = sigmoidf_(acc[6 + uh][r]);
                    c[uh][r] = fv * c[uh][r] + iv * gv;
                    hbb[w][4 * q + r][n + 16 * uh] = f2bf(ov * tanhf_fast(c[uh][r]));
                }
#pragma unroll
            for (int r = 0; r < 4; ++r) xc[r] = xnx[r];
        }

        // P tile = bo + h @ Wo -> LDS, unit-major pair layout
        {
            const short8 A = *(const short8*)&hbb[w][n][8 * q];
            f32x4 accp[6];
#pragma unroll
            for (int tt = 0; tt < 6; ++tt) {
#pragma unroll
                for (int r = 0; r < 4; ++r) accp[tt][r] = bo_l[tt];
                accp[tt] = __builtin_amdgcn_mfma_f32_16x16x32_bf16(A, Bwo[tt].v, accp[tt], 0, 0, 0);
            }
#pragma unroll
            for (int r = 0; r < 4; ++r) {
                const int tr = wt0 + 4 * q + r;
#pragma unroll
                for (int tt = 0; tt < 6; ++tt)
                    Pl[tr][pcol[tt]] = (_Float16)accp[tt][r];
            }
        }
        // release this tile to the consumer (DS ops in-order; release fences)
        __hip_atomic_store(&flags[tile], 1u, __ATOMIC_RELEASE, __HIP_MEMORY_SCOPE_WORKGROUP);
    }

    if (w != 0) return;                          // producers retire

    // ================= phase 2: outer LSTM + head (wave 0) =================
    const int half = lane >> 5;                  // 0: gates i,f  1: gates g,o
    const int sub  = lane & 31;
    const int u    = (sub < U2) ? sub : U2 - 1;

    float wA[U2], wB[U2];                        // 48 weight VGPRs
#pragma unroll
    for (int k = 0; k < U2; ++k) {
        wA[k] = Uo[k * G2 + (2 * half) * U2 + u];
        wB[k] = Uo[k * G2 + (2 * half + 1) * U2 + u];
    }

    // one ds_read_b64 per row: all 4 gate pre-activations of unit u
    auto ldrow = [&](int t) -> f32x4 {
        const uint2 raw = *reinterpret_cast<const uint2*>(&Pl[t][4 * u]);
        h2x a, c2; a.u32 = raw.x; c2.u32 = raw.y;
        f32x4 r;
        r[0] = (float)a.h[0];  r[1] = (float)a.h[1];   // i, f
        r[2] = (float)c2.h[0]; r[3] = (float)c2.h[1];  // g, o
        return r;
    };

    // tile 0 produced by this wave itself: rows 0..15 are ready.
    f32x4 cur = ldrow(0);
    float cu, hu;
    {   // peeled t = 0 (h == 0, c == 0) -- all gates lane-local, no shuffle
        const float ig = sigmoidf_(cur[0]);
        const float gg = tanhf_fast(cur[2]);
        const float og = sigmoidf_(cur[3]);
        cu = ig * gg;
        hu = og * tanhf_fast(cu);
    }
    int wtile = 0;
    f32x4 nxt = ldrow((1 < len) ? 1 : 0);        // prefetch row for t=1

#pragma unroll 1
    for (int t = 1; t < len; ++t) {
        // prefetch row t+1 (clamped); spin only when crossing into a new tile
        const int tn = (t + 1 < len) ? (t + 1) : (len - 1);
        const int ttile = tn >> 4;
        if (ttile != wtile) {                    // wave-uniform
            while (__hip_atomic_load(&flags[ttile], __ATOMIC_ACQUIRE,
                                     __HIP_MEMORY_SCOPE_WORKGROUP) == 0u)
                __builtin_amdgcn_s_sleep(1);
            wtile = ttile;
        }
        const f32x4 pf = ldrow(tn);

        // batch the h broadcast (independent readlanes, then FMAs)
        float hk[U2];
#pragma unroll
        for (int k = 0; k < U2; ++k)
            hk[k] = __int_as_float(__builtin_amdgcn_readlane(__float_as_int(hu), k));

        const float pA = half ? nxt[2] : nxt[0];
        const float pB = half ? nxt[3] : nxt[1];
        float a0 = pA, a1 = 0.0f, a2 = 0.0f, a3 = 0.0f;
        float b0 = pB, b1 = 0.0f, b2 = 0.0f, b3 = 0.0f;
#pragma unroll
        for (int k = 0; k < U2; k += 4) {        // 4 chains x depth 6
            a0 += hk[k]     * wA[k];     b0 += hk[k]     * wB[k];
            a1 += hk[k + 1] * wA[k + 1]; b1 += hk[k + 1] * wB[k + 1];
            a2 += hk[k + 2] * wA[k + 2]; b2 += hk[k + 2] * wB[k + 2];
            a3 += hk[k + 3] * wA[k + 3]; b3 += hk[k + 3] * wB[k + 3];
        }
        const float zA = (a0 + a1) + (a2 + a3);  // half0: z_i ; half1: z_g
        const float zB = (b0 + b1) + (b2 + b3);  // half0: z_f ; half1: z_o
        const float oA = __shfl_xor(zA, 32);
        const float oB = __shfl_xor(zB, 32);

        const float z_i = half ? oA : zA;
        const float z_f = half ? oB : zB;
        const float z_g = half ? zA : oA;
        const float z_o = half ? zB : oB;

        const float ig = sigmoidf_(z_i);
        const float fg = sigmoidf_(z_f);
        const float gg = tanhf_fast(z_g);
        const float og = sigmoidf_(z_o);
        cu = fg * cu + ig * gg;
        hu = og * tanhf_fast(cu);                // identical on both halves

        nxt = pf;
    }

    // dense sigmoid head
    float acc = bd[0];
#pragma unroll
    for (int k = 0; k < U2; ++k)
        acc += __int_as_float(__builtin_amdgcn_readlane(__float_as_int(hu), k)) * Wd[k];
    if (lane == 0) out[b] = sigmoidf_(acc);
}

extern "C" void kernel_launch(void* const* d_in, const int* in_sizes, int n_in,
                              void* d_out, int out_size, void* d_ws, size_t ws_size,
                              hipStream_t stream) {
    const float* x       = (const float*)d_in[0];
    const int*   lengths = (const int*)  d_in[1];
    const float* Wi      = (const float*)d_in[2];
    const float* Ui      = (const float*)d_in[3];
    const float* bi      = (const float*)d_in[4];
    const float* Wo      = (const float*)d_in[5];
    const float* Uo      = (const float*)d_in[6];
    const float* bo      = (const float*)d_in[7];
    const float* Wd      = (const float*)d_in[8];
    const float* bd      = (const float*)d_in[9];
    float* out = (float*)d_out;

    fused_kernel<<<dim3(B_), dim3(512), 0, stream>>>(
        x, lengths, Wi, Ui, bi, Wo, Uo, bo, Wd, bd, out);
}